// Round 1
// baseline (713.681 us; speedup 1.0000x reference)
//
#include <hip/hip_runtime.h>

#define DM 1024     // D_MODEL
#define NH 16       // NUM_HEADS
#define DK 64       // D_K

// ---------------------------------------------------------------------------
// GEMM (NT): C[M,N] = A[M,K] @ Bw[N,K]^T + bias[N]
// Both A rows and Bw rows are contiguous along K -> coalesced float4 loads.
// Tiles 64x64x32, 256 threads (16x16), 4x4 accumulator per thread.
// LDS stored K-outer ([k][m]) with +1 pad to break store-bank conflicts.
// ---------------------------------------------------------------------------
__global__ __launch_bounds__(256) void gemm_nt(
    const float* __restrict__ A, const float* __restrict__ Bw,
    const float* __restrict__ bias, float* __restrict__ C,
    int M, int N, int K)
{
    __shared__ float As[32][65];
    __shared__ float Bs[32][65];
    const int tid = threadIdx.x;
    const int tx = tid & 15, ty = tid >> 4;
    const int row0 = blockIdx.y * 64, col0 = blockIdx.x * 64;
    const int lr = tid >> 2;        // 0..63 (row within tile)
    const int lq = (tid & 3) * 8;   // k offset: 0,8,16,24

    float acc[4][4] = {};

    const float* Arow = A + (size_t)(row0 + lr) * K + lq;
    const float* Brow = Bw + (size_t)(col0 + lr) * K + lq;

    for (int kt = 0; kt < K; kt += 32) {
        const float4 a0 = *reinterpret_cast<const float4*>(Arow + kt);
        const float4 a1 = *reinterpret_cast<const float4*>(Arow + kt + 4);
        const float4 b0 = *reinterpret_cast<const float4*>(Brow + kt);
        const float4 b1 = *reinterpret_cast<const float4*>(Brow + kt + 4);
        __syncthreads();
        As[lq+0][lr] = a0.x; As[lq+1][lr] = a0.y; As[lq+2][lr] = a0.z; As[lq+3][lr] = a0.w;
        As[lq+4][lr] = a1.x; As[lq+5][lr] = a1.y; As[lq+6][lr] = a1.z; As[lq+7][lr] = a1.w;
        Bs[lq+0][lr] = b0.x; Bs[lq+1][lr] = b0.y; Bs[lq+2][lr] = b0.z; Bs[lq+3][lr] = b0.w;
        Bs[lq+4][lr] = b1.x; Bs[lq+5][lr] = b1.y; Bs[lq+6][lr] = b1.z; Bs[lq+7][lr] = b1.w;
        __syncthreads();
        #pragma unroll
        for (int kk = 0; kk < 32; ++kk) {
            float av[4], bv[4];
            #pragma unroll
            for (int i = 0; i < 4; ++i) av[i] = As[kk][ty * 4 + i];
            #pragma unroll
            for (int j = 0; j < 4; ++j) bv[j] = Bs[kk][tx * 4 + j];
            #pragma unroll
            for (int i = 0; i < 4; ++i)
                #pragma unroll
                for (int j = 0; j < 4; ++j)
                    acc[i][j] += av[i] * bv[j];
        }
    }

    #pragma unroll
    for (int i = 0; i < 4; ++i) {
        const size_t crow = (size_t)(row0 + ty * 4 + i) * N + col0;
        #pragma unroll
        for (int j = 0; j < 4; ++j) {
            C[crow + tx * 4 + j] = acc[i][j] + bias[col0 + tx * 4 + j];
        }
    }
}

// ---------------------------------------------------------------------------
// K^T V partials per (b,h) over an s-chunk:
//   Mpart[chunk,bh,d1,d2] = sum_{s in chunk, mask=1} K[b,s,h*64+d1] * V[b,s,h*64+d2]
//   cvpart[chunk,bh,e]    = sum_{s in chunk, mask=0} V[b,s,h*64+e]
// Deterministic: partials reduced by reduce_m (no float atomics).
// ---------------------------------------------------------------------------
__global__ __launch_bounds__(256) void ktv_partial(
    const float* __restrict__ Kb, const float* __restrict__ Vb,
    const int* __restrict__ mask, float* __restrict__ Mpart,
    float* __restrict__ cvpart, int S, int schunk)
{
    __shared__ float Ks[16][64];
    __shared__ float Vs[16][64];
    __shared__ float cvs[16][64];
    const int bh = blockIdx.x, chunk = blockIdx.y, BH = gridDim.x;
    const int b = bh >> 4, h = bh & 15;
    const int tid = threadIdx.x;
    const int tx = tid & 15, ty = tid >> 4;   // ty also = row-in-chunk for loads
    const int s0 = chunk * schunk;

    float acc[4][4] = {};
    float cv[4] = {0.f, 0.f, 0.f, 0.f};

    for (int sc = 0; sc < schunk; sc += 16) {
        const int s = s0 + sc + ty;
        const size_t rowoff = (size_t)(b * S + s) * DM + h * DK + tx * 4;
        float4 kv = *reinterpret_cast<const float4*>(Kb + rowoff);
        const float4 vv = *reinterpret_cast<const float4*>(Vb + rowoff);
        if (mask[b * S + s] == 0) {
            cv[0] += vv.x; cv[1] += vv.y; cv[2] += vv.z; cv[3] += vv.w;
            kv = make_float4(0.f, 0.f, 0.f, 0.f);
        }
        __syncthreads();
        *reinterpret_cast<float4*>(&Ks[ty][tx * 4]) = kv;
        *reinterpret_cast<float4*>(&Vs[ty][tx * 4]) = vv;
        __syncthreads();
        #pragma unroll
        for (int ss = 0; ss < 16; ++ss) {
            float kvv[4], vvv[4];
            #pragma unroll
            for (int i = 0; i < 4; ++i) kvv[i] = Ks[ss][ty * 4 + i];
            #pragma unroll
            for (int j = 0; j < 4; ++j) vvv[j] = Vs[ss][tx * 4 + j];
            #pragma unroll
            for (int i = 0; i < 4; ++i)
                #pragma unroll
                for (int j = 0; j < 4; ++j)
                    acc[i][j] += kvv[i] * vvv[j];
        }
    }

    const size_t mbase = ((size_t)chunk * BH + bh) * (DK * DK);
    #pragma unroll
    for (int i = 0; i < 4; ++i)
        #pragma unroll
        for (int j = 0; j < 4; ++j)
            Mpart[mbase + (size_t)(ty * 4 + i) * DK + tx * 4 + j] = acc[i][j];

    // reduce cv within block: cvs[row-group][e]
    __syncthreads();
    #pragma unroll
    for (int j = 0; j < 4; ++j) cvs[ty][tx * 4 + j] = cv[j];
    __syncthreads();
    if (tid < DK) {
        float s = 0.f;
        #pragma unroll
        for (int r = 0; r < 16; ++r) s += cvs[r][tid];
        cvpart[((size_t)chunk * BH + bh) * DK + tid] = s;
    }
}

// ---------------------------------------------------------------------------
// Reduce partials: Mm[bh] = sum_c Mpart[c,bh] * (1/sqrt(DK)); cvec likewise.
// ---------------------------------------------------------------------------
__global__ __launch_bounds__(256) void reduce_m(
    const float* __restrict__ Mpart, const float* __restrict__ cvpart,
    float* __restrict__ Mm, float* __restrict__ cvec, int nchunk, int BH)
{
    const int bh = blockIdx.x;
    const int tid = threadIdx.x;
    for (int e = tid; e < DK * DK; e += 256) {
        float s = 0.f;
        for (int c = 0; c < nchunk; ++c)
            s += Mpart[((size_t)c * BH + bh) * (DK * DK) + e];
        Mm[(size_t)bh * DK * DK + e] = s * 0.125f;   // 1/sqrt(64)
    }
    if (tid < DK) {
        float s = 0.f;
        for (int c = 0; c < nchunk; ++c)
            s += cvpart[((size_t)c * BH + bh) * DK + tid];
        cvec[bh * DK + tid] = s;
    }
}

// ---------------------------------------------------------------------------
// attn[b, s, h*64+e] = sum_d Q[b,s,h*64+d] * Mm[bh,d,e]  - 1e9 * cvec[bh,e]
// One block per (64 s-rows, bh). K = 64, single LDS stage.
// ---------------------------------------------------------------------------
__global__ __launch_bounds__(256) void qm_attn(
    const float* __restrict__ Qb, const float* __restrict__ Mm,
    const float* __restrict__ cvec, float* __restrict__ attn, int S)
{
    __shared__ float Qs[64][65];
    __shared__ float Ms[64][65];
    const int bh = blockIdx.y;
    const int b = bh >> 4, h = bh & 15;
    const int s0 = blockIdx.x * 64;
    const int tid = threadIdx.x;
    const int tx = tid & 15, ty = tid >> 4;
    const int lr = tid >> 2;   // 0..63
    const int lc = tid & 3;    // 4 threads per row

    #pragma unroll
    for (int u = 0; u < 4; ++u) {
        const int f = (lc + u * 4) * 4;   // float col 0..60 step 4
        const float4 qv = *reinterpret_cast<const float4*>(
            Qb + (size_t)(b * S + s0 + lr) * DM + h * DK + f);
        Qs[lr][f + 0] = qv.x; Qs[lr][f + 1] = qv.y; Qs[lr][f + 2] = qv.z; Qs[lr][f + 3] = qv.w;
        const float4 mv = *reinterpret_cast<const float4*>(
            Mm + (size_t)bh * DK * DK + (size_t)lr * DK + f);
        Ms[lr][f + 0] = mv.x; Ms[lr][f + 1] = mv.y; Ms[lr][f + 2] = mv.z; Ms[lr][f + 3] = mv.w;
    }
    __syncthreads();

    float acc[4][4] = {};
    #pragma unroll 8
    for (int kk = 0; kk < 64; ++kk) {
        float qv[4], mv[4];
        #pragma unroll
        for (int i = 0; i < 4; ++i) qv[i] = Qs[ty * 4 + i][kk];
        #pragma unroll
        for (int j = 0; j < 4; ++j) mv[j] = Ms[kk][tx * 4 + j];
        #pragma unroll
        for (int i = 0; i < 4; ++i)
            #pragma unroll
            for (int j = 0; j < 4; ++j)
                acc[i][j] += qv[i] * mv[j];
    }

    float cvv[4];
    #pragma unroll
    for (int j = 0; j < 4; ++j) cvv[j] = -1.0e9f * cvec[bh * DK + tx * 4 + j];

    #pragma unroll
    for (int i = 0; i < 4; ++i) {
        const size_t orow = (size_t)(b * S + s0 + ty * 4 + i) * DM + h * DK;
        #pragma unroll
        for (int j = 0; j < 4; ++j)
            attn[orow + tx * 4 + j] = acc[i][j] + cvv[j];
    }
}

// ---------------------------------------------------------------------------
extern "C" void kernel_launch(void* const* d_in, const int* in_sizes, int n_in,
                              void* d_out, int out_size, void* d_ws, size_t ws_size,
                              hipStream_t stream)
{
    const float* q    = (const float*)d_in[0];
    const float* k    = (const float*)d_in[1];
    const float* v    = (const float*)d_in[2];
    const int*   mask = (const int*)  d_in[3];
    const float* Wq   = (const float*)d_in[4];
    const float* bq   = (const float*)d_in[5];
    const float* Wk   = (const float*)d_in[6];
    const float* bk   = (const float*)d_in[7];
    const float* Wv   = (const float*)d_in[8];
    const float* bv   = (const float*)d_in[9];
    const float* Wo   = (const float*)d_in[10];
    const float* bo   = (const float*)d_in[11];
    float* out = (float*)d_out;

    const int BS = in_sizes[0] / DM;   // B*S = 4096
    const int B  = 2;
    const int S  = BS / B;             // 2048
    const int BH = B * NH;             // 32
    const int SCHUNK = 256;
    const int NCHUNK = S / SCHUNK;     // 8

    float* ws = (float*)d_ws;
    float* Q     = ws;                         // BS*DM
    float* Kp    = Q    + (size_t)BS * DM;     // BS*DM
    float* Vp    = Kp   + (size_t)BS * DM;     // BS*DM
    float* attn  = Vp   + (size_t)BS * DM;     // BS*DM
    float* Mpart = attn + (size_t)BS * DM;     // NCHUNK*BH*DK*DK
    float* cvprt = Mpart + (size_t)NCHUNK * BH * DK * DK;  // NCHUNK*BH*DK
    float* Mm    = cvprt + (size_t)NCHUNK * BH * DK;       // BH*DK*DK
    float* cvec  = Mm   + (size_t)BH * DK * DK;            // BH*DK

    const dim3 blk(256);
    const dim3 gProj(DM / 64, BS / 64);

    // QKV projections: X @ W^T + b
    gemm_nt<<<gProj, blk, 0, stream>>>(q, Wq, bq, Q,  BS, DM, DM);
    gemm_nt<<<gProj, blk, 0, stream>>>(k, Wk, bk, Kp, BS, DM, DM);
    gemm_nt<<<gProj, blk, 0, stream>>>(v, Wv, bv, Vp, BS, DM, DM);

    // per-head K^T V (masked) partials + reduction
    ktv_partial<<<dim3(BH, NCHUNK), blk, 0, stream>>>(Kp, Vp, mask, Mpart, cvprt, S, SCHUNK);
    reduce_m<<<dim3(BH), blk, 0, stream>>>(Mpart, cvprt, Mm, cvec, NCHUNK, BH);

    // attn = Q @ Mm (per head) + mask-correction
    qm_attn<<<dim3(S / 64, BH), blk, 0, stream>>>(Q, Mm, cvec, attn, S);

    // output projection
    gemm_nt<<<gProj, blk, 0, stream>>>(attn, Wo, bo, out, BS, DM, DM);
}

// Round 2
// 169.692 us; speedup vs baseline: 4.2057x; 4.2057x over previous
//
#include <hip/hip_runtime.h>
#include <stdint.h>

#define DM 1024     // D_MODEL
#define NH 16       // NUM_HEADS
#define DK 64       // D_K

typedef __attribute__((ext_vector_type(8))) __bf16 bf16x8;
typedef __attribute__((ext_vector_type(4))) float f32x4;

__device__ __forceinline__ float bf2f(unsigned short u) {
    union { uint32_t i; float f; } x; x.i = ((uint32_t)u) << 16; return x.f;
}
__device__ __forceinline__ unsigned short f2bf(float f) {
    union { float f; uint32_t i; } x; x.f = f;
    uint32_t r = x.i + 0x7fffu + ((x.i >> 16) & 1u);   // RNE
    return (unsigned short)(r >> 16);
}

__device__ __forceinline__ void gl2lds16(const void* g, void* l) {
    __builtin_amdgcn_global_load_lds(
        (const __attribute__((address_space(1))) void*)g,
        (__attribute__((address_space(3))) void*)l, 16, 0, 0);
}

__device__ __forceinline__ f32x4 mfma_bf16(bf16x8 a, bf16x8 b, f32x4 c) {
    return __builtin_amdgcn_mfma_f32_16x16x32_bf16(a, b, c, 0, 0, 0);
}

__device__ __forceinline__ void store_out(float* p, float v) { *p = v; }
__device__ __forceinline__ void store_out(unsigned short* p, float v) { *p = f2bf(v); }

// ---------------------------------------------------------------------------
// fp32 -> bf16 conversion, up to 4 tensors per launch (each n4per float4's).
// ---------------------------------------------------------------------------
struct Cvt4Args {
    const float* src[4];
    unsigned short* dst[4];
};

__global__ __launch_bounds__(256) void cvt4(Cvt4Args a, int n4per, int nseg) {
    const int t = blockIdx.x * blockDim.x + threadIdx.x;
    const int seg = t / n4per;
    if (seg >= nseg) return;
    const int off = t - seg * n4per;
    const float4 v = reinterpret_cast<const float4*>(a.src[seg])[off];
    ushort4 o;
    o.x = f2bf(v.x); o.y = f2bf(v.y); o.z = f2bf(v.z); o.w = f2bf(v.w);
    reinterpret_cast<ushort4*>(a.dst[seg])[off] = o;
}

// ---------------------------------------------------------------------------
// Batched NT GEMM, bf16 in, MFMA 16x16x32, fp32 accum:
//   C[z][M,N] = A[z][M,K] @ W[z][N,K]^T + bias[z][N]
// 128x128 tile, BK=64, 4 waves (2x2), 4x4 16x16 frags/wave.
// m97 structure: global_load_lds width=16 into linear LDS, 2-barrier K-loop.
// ---------------------------------------------------------------------------
template<typename OutT>
struct GemmArgs {
    const unsigned short* A[3];
    const unsigned short* W[3];
    const float* bias[3];
    OutT* C[3];
};

template<typename OutT>
__global__ __launch_bounds__(256) void gemm_nt_bf16(GemmArgs<OutT> g, int M, int N, int K)
{
    const unsigned short* __restrict__ A  = g.A[blockIdx.z];
    const unsigned short* __restrict__ Bw = g.W[blockIdx.z];
    const float* __restrict__ bias = g.bias[blockIdx.z];
    OutT* __restrict__ C = g.C[blockIdx.z];

    __shared__ unsigned short As[128 * 64];   // [row][k] row-major, 16 KB
    __shared__ unsigned short Bs[128 * 64];   // [col][k] row-major, 16 KB

    const int tid  = threadIdx.x;
    const int lane = tid & 63;
    const int w    = tid >> 6;          // wave 0..3
    const int wr   = w >> 1, wc = w & 1;
    const int row0 = blockIdx.y * 128;
    const int col0 = blockIdx.x * 128;

    f32x4 acc[4][4];
    #pragma unroll
    for (int m = 0; m < 4; ++m)
        #pragma unroll
        for (int n = 0; n < 4; ++n)
            acc[m][n] = (f32x4){0.f, 0.f, 0.f, 0.f};

    const int srow = lane >> 3;          // 0..7: row within 8-row stripe
    const int scol = (lane & 7) * 8;     // element offset within 64-elem row

    for (int kt = 0; kt < K; kt += 64) {
        // stage A,B tiles: per wave 4 issues per matrix; each covers 8 rows
        #pragma unroll
        for (int i = 0; i < 4; ++i) {
            const int blkr = w * 4 + i;              // stripe 0..15
            const int r = blkr * 8 + srow;
            gl2lds16(A  + (size_t)(row0 + r) * K + kt + scol, &As[blkr * 512]);
            gl2lds16(Bw + (size_t)(col0 + r) * K + kt + scol, &Bs[blkr * 512]);
        }
        __syncthreads();   // drains vmcnt -> staged tiles visible

        #pragma unroll
        for (int kk = 0; kk < 2; ++kk) {
            const int ko = kk * 32 + (lane >> 4) * 8;
            bf16x8 af[4], bf[4];
            #pragma unroll
            for (int m = 0; m < 4; ++m)
                af[m] = *reinterpret_cast<const bf16x8*>(&As[(wr * 64 + m * 16 + (lane & 15)) * 64 + ko]);
            #pragma unroll
            for (int n = 0; n < 4; ++n)
                bf[n] = *reinterpret_cast<const bf16x8*>(&Bs[(wc * 64 + n * 16 + (lane & 15)) * 64 + ko]);
            #pragma unroll
            for (int m = 0; m < 4; ++m)
                #pragma unroll
                for (int n = 0; n < 4; ++n)
                    acc[m][n] = mfma_bf16(af[m], bf[n], acc[m][n]);
        }
        __syncthreads();   // all waves done reading before next stage
    }

    // epilogue: C/D layout col=lane&15, row=(lane>>4)*4+reg
    const int cr = (lane >> 4) * 4;
    const int cc = lane & 15;
    #pragma unroll
    for (int n = 0; n < 4; ++n) {
        const int col = col0 + wc * 64 + n * 16 + cc;
        const float bv = bias[col];
        #pragma unroll
        for (int m = 0; m < 4; ++m) {
            const int rowb = row0 + wr * 64 + m * 16 + cr;
            #pragma unroll
            for (int r = 0; r < 4; ++r)
                store_out(&C[(size_t)(rowb + r) * N + col], acc[m][n][r] + bv);
        }
    }
}

// ---------------------------------------------------------------------------
// K^T V partials per (b,h) over an s-chunk (bf16 in, fp32 accum/out):
//   Mpart[chunk,bh,d1,d2] = sum_{s in chunk, mask=1} K[b,s,h*64+d1]*V[b,s,h*64+d2]
//   cvpart[chunk,bh,e]    = sum_{s in chunk, mask=0} V[b,s,h*64+e]
// ---------------------------------------------------------------------------
__global__ __launch_bounds__(256) void ktv_partial(
    const unsigned short* __restrict__ Kb, const unsigned short* __restrict__ Vb,
    const int* __restrict__ mask, float* __restrict__ Mpart,
    float* __restrict__ cvpart, int S, int schunk)
{
    __shared__ float Ks[16][64];
    __shared__ float Vs[16][64];
    __shared__ float cvs[16][64];
    const int bh = blockIdx.x, chunk = blockIdx.y, BH = gridDim.x;
    const int b = bh >> 4, h = bh & 15;
    const int tid = threadIdx.x;
    const int tx = tid & 15, ty = tid >> 4;
    const int s0 = chunk * schunk;

    float acc[4][4] = {};
    float cv[4] = {0.f, 0.f, 0.f, 0.f};

    for (int sc = 0; sc < schunk; sc += 16) {
        const int s = s0 + sc + ty;
        const size_t rowoff = (size_t)(b * S + s) * DM + h * DK + tx * 4;
        const ushort4 kraw = *reinterpret_cast<const ushort4*>(Kb + rowoff);
        const ushort4 vraw = *reinterpret_cast<const ushort4*>(Vb + rowoff);
        float kv[4] = {bf2f(kraw.x), bf2f(kraw.y), bf2f(kraw.z), bf2f(kraw.w)};
        const float vv[4] = {bf2f(vraw.x), bf2f(vraw.y), bf2f(vraw.z), bf2f(vraw.w)};
        if (mask[b * S + s] == 0) {
            #pragma unroll
            for (int j = 0; j < 4; ++j) { cv[j] += vv[j]; kv[j] = 0.f; }
        }
        __syncthreads();
        #pragma unroll
        for (int j = 0; j < 4; ++j) { Ks[ty][tx * 4 + j] = kv[j]; Vs[ty][tx * 4 + j] = vv[j]; }
        __syncthreads();
        #pragma unroll
        for (int ss = 0; ss < 16; ++ss) {
            float kvv[4], vvv[4];
            #pragma unroll
            for (int i = 0; i < 4; ++i) kvv[i] = Ks[ss][ty * 4 + i];
            #pragma unroll
            for (int j = 0; j < 4; ++j) vvv[j] = Vs[ss][tx * 4 + j];
            #pragma unroll
            for (int i = 0; i < 4; ++i)
                #pragma unroll
                for (int j = 0; j < 4; ++j)
                    acc[i][j] += kvv[i] * vvv[j];
        }
    }

    const size_t mbase = ((size_t)chunk * BH + bh) * (DK * DK);
    #pragma unroll
    for (int i = 0; i < 4; ++i)
        #pragma unroll
        for (int j = 0; j < 4; ++j)
            Mpart[mbase + (size_t)(ty * 4 + i) * DK + tx * 4 + j] = acc[i][j];

    __syncthreads();
    #pragma unroll
    for (int j = 0; j < 4; ++j) cvs[ty][tx * 4 + j] = cv[j];
    __syncthreads();
    if (tid < DK) {
        float s = 0.f;
        #pragma unroll
        for (int r = 0; r < 16; ++r) s += cvs[r][tid];
        cvpart[((size_t)chunk * BH + bh) * DK + tid] = s;
    }
}

// ---------------------------------------------------------------------------
// Reduce partials: Mm[bh] = sum_c Mpart[c,bh] * (1/sqrt(DK)); cvec likewise.
// ---------------------------------------------------------------------------
__global__ __launch_bounds__(256) void reduce_m(
    const float* __restrict__ Mpart, const float* __restrict__ cvpart,
    float* __restrict__ Mm, float* __restrict__ cvec, int nchunk, int BH)
{
    const int bh = blockIdx.x;
    const int tid = threadIdx.x;
    for (int e = tid; e < DK * DK; e += 256) {
        float s = 0.f;
        for (int c = 0; c < nchunk; ++c)
            s += Mpart[((size_t)c * BH + bh) * (DK * DK) + e];
        Mm[(size_t)bh * DK * DK + e] = s * 0.125f;   // 1/sqrt(64)
    }
    if (tid < DK) {
        float s = 0.f;
        for (int c = 0; c < nchunk; ++c)
            s += cvpart[((size_t)c * BH + bh) * DK + tid];
        cvec[bh * DK + tid] = s;
    }
}

// ---------------------------------------------------------------------------
// attn[b,s,h*64+e] = sum_d Q[b,s,h*64+d]*Mm[bh,d,e] - 1e9*cvec[bh,e]
// Q bf16 in, attn bf16 out, fp32 math.
// ---------------------------------------------------------------------------
__global__ __launch_bounds__(256) void qm_attn(
    const unsigned short* __restrict__ Qb, const float* __restrict__ Mm,
    const float* __restrict__ cvec, unsigned short* __restrict__ attn, int S)
{
    __shared__ float Qs[64][65];
    __shared__ float Ms[64][65];
    const int bh = blockIdx.y;
    const int b = bh >> 4, h = bh & 15;
    const int s0 = blockIdx.x * 64;
    const int tid = threadIdx.x;
    const int tx = tid & 15, ty = tid >> 4;
    const int lr = tid >> 2;   // 0..63
    const int lc = tid & 3;    // 4 threads per row

    #pragma unroll
    for (int u = 0; u < 4; ++u) {
        const int f = (lc + u * 4) * 4;   // col 0..60 step 4
        const ushort4 qraw = *reinterpret_cast<const ushort4*>(
            Qb + (size_t)(b * S + s0 + lr) * DM + h * DK + f);
        Qs[lr][f + 0] = bf2f(qraw.x); Qs[lr][f + 1] = bf2f(qraw.y);
        Qs[lr][f + 2] = bf2f(qraw.z); Qs[lr][f + 3] = bf2f(qraw.w);
        const float4 mv = *reinterpret_cast<const float4*>(
            Mm + (size_t)bh * DK * DK + (size_t)lr * DK + f);
        Ms[lr][f + 0] = mv.x; Ms[lr][f + 1] = mv.y; Ms[lr][f + 2] = mv.z; Ms[lr][f + 3] = mv.w;
    }
    __syncthreads();

    float acc[4][4] = {};
    #pragma unroll 8
    for (int kk = 0; kk < 64; ++kk) {
        float qv[4], mv[4];
        #pragma unroll
        for (int i = 0; i < 4; ++i) qv[i] = Qs[ty * 4 + i][kk];
        #pragma unroll
        for (int j = 0; j < 4; ++j) mv[j] = Ms[kk][tx * 4 + j];
        #pragma unroll
        for (int i = 0; i < 4; ++i)
            #pragma unroll
            for (int j = 0; j < 4; ++j)
                acc[i][j] += qv[i] * mv[j];
    }

    float cvv[4];
    #pragma unroll
    for (int j = 0; j < 4; ++j) cvv[j] = -1.0e9f * cvec[bh * DK + tx * 4 + j];

    #pragma unroll
    for (int i = 0; i < 4; ++i) {
        const size_t orow = (size_t)(b * S + s0 + ty * 4 + i) * DM + h * DK;
        ushort4 o;
        o.x = f2bf(acc[i][0] + cvv[0]);
        o.y = f2bf(acc[i][1] + cvv[1]);
        o.z = f2bf(acc[i][2] + cvv[2]);
        o.w = f2bf(acc[i][3] + cvv[3]);
        *reinterpret_cast<ushort4*>(&attn[orow + tx * 4]) = o;
    }
}

// ---------------------------------------------------------------------------
extern "C" void kernel_launch(void* const* d_in, const int* in_sizes, int n_in,
                              void* d_out, int out_size, void* d_ws, size_t ws_size,
                              hipStream_t stream)
{
    const float* q    = (const float*)d_in[0];
    const float* k    = (const float*)d_in[1];
    const float* v    = (const float*)d_in[2];
    const int*   mask = (const int*)  d_in[3];
    const float* Wq   = (const float*)d_in[4];
    const float* bq   = (const float*)d_in[5];
    const float* Wk   = (const float*)d_in[6];
    const float* bk   = (const float*)d_in[7];
    const float* Wv   = (const float*)d_in[8];
    const float* bv   = (const float*)d_in[9];
    const float* Wo   = (const float*)d_in[10];
    const float* bo   = (const float*)d_in[11];
    float* out = (float*)d_out;

    const int BS = in_sizes[0] / DM;   // B*S = 4096
    const int B  = 2;
    const int S  = BS / B;             // 2048
    const int BH = B * NH;             // 32
    const int SCHUNK = 256;
    const int NCHUNK = S / SCHUNK;     // 8
    const size_t BSDM = (size_t)BS * DM;   // 4M
    const size_t DMDM = (size_t)DM * DM;   // 1M

    unsigned short* ws = (unsigned short*)d_ws;
    unsigned short* qb   = ws;                  // bf16 copies of inputs
    unsigned short* kb   = qb  + BSDM;
    unsigned short* vb   = kb  + BSDM;
    unsigned short* Wqb  = vb  + BSDM;
    unsigned short* Wkb  = Wqb + DMDM;
    unsigned short* Wvb  = Wkb + DMDM;
    unsigned short* Wob  = Wvb + DMDM;
    unsigned short* Qp   = Wob + DMDM;          // projection outputs (bf16)
    unsigned short* Kp   = Qp  + BSDM;
    unsigned short* Vp   = Kp  + BSDM;
    unsigned short* attnb = qb;                 // alias: qb dead after projections
    float* Mpart = (float*)kb;                  // alias: kb dead after projections
    float* cvprt = Mpart + (size_t)NCHUNK * BH * DK * DK;
    float* Mm    = cvprt + (size_t)NCHUNK * BH * DK;
    float* cvec  = Mm    + (size_t)BH * DK * DK;

    const dim3 blk(256);

    // fp32 -> bf16 conversions (2 batched launches)
    Cvt4Args c1;
    c1.src[0] = q;  c1.src[1] = k;  c1.src[2] = v;  c1.src[3] = nullptr;
    c1.dst[0] = qb; c1.dst[1] = kb; c1.dst[2] = vb; c1.dst[3] = nullptr;
    cvt4<<<dim3(3 * (BSDM / 4) / 256), blk, 0, stream>>>(c1, (int)(BSDM / 4), 3);
    Cvt4Args c2;
    c2.src[0] = Wq;  c2.src[1] = Wk;  c2.src[2] = Wv;  c2.src[3] = Wo;
    c2.dst[0] = Wqb; c2.dst[1] = Wkb; c2.dst[2] = Wvb; c2.dst[3] = Wob;
    cvt4<<<dim3(4 * (DMDM / 4) / 256), blk, 0, stream>>>(c2, (int)(DMDM / 4), 4);

    // batched QKV projections (grid.z = 3 -> 768 blocks, 3/CU)
    GemmArgs<unsigned short> ga;
    ga.A[0] = qb;  ga.A[1] = kb;  ga.A[2] = vb;
    ga.W[0] = Wqb; ga.W[1] = Wkb; ga.W[2] = Wvb;
    ga.bias[0] = bq; ga.bias[1] = bk; ga.bias[2] = bv;
    ga.C[0] = Qp;  ga.C[1] = Kp;  ga.C[2] = Vp;
    gemm_nt_bf16<unsigned short><<<dim3(DM / 128, BS / 128, 3), blk, 0, stream>>>(ga, BS, DM, DM);

    // per-head K^T V (masked) partials + reduction
    ktv_partial<<<dim3(BH, NCHUNK), blk, 0, stream>>>(Kp, Vp, mask, Mpart, cvprt, S, SCHUNK);
    reduce_m<<<dim3(BH), blk, 0, stream>>>(Mpart, cvprt, Mm, cvec, NCHUNK, BH);

    // attn = Q @ Mm (per head) + mask correction, bf16 out
    qm_attn<<<dim3(S / 64, BH), blk, 0, stream>>>(Qp, Mm, cvec, attnb, S);

    // output projection (fp32 out)
    GemmArgs<float> gf;
    gf.A[0] = attnb; gf.A[1] = nullptr; gf.A[2] = nullptr;
    gf.W[0] = Wob;   gf.W[1] = nullptr; gf.W[2] = nullptr;
    gf.bias[0] = bo; gf.bias[1] = nullptr; gf.bias[2] = nullptr;
    gf.C[0] = out;   gf.C[1] = nullptr;  gf.C[2] = nullptr;
    gemm_nt_bf16<float><<<dim3(DM / 128, BS / 128, 1), blk, 0, stream>>>(gf, BS, DM, DM);
}

// Round 3
// 145.003 us; speedup vs baseline: 4.9218x; 1.1703x over previous
//
#include <hip/hip_runtime.h>
#include <stdint.h>

#define DM 1024     // D_MODEL
#define NH 16       // NUM_HEADS
#define DK 64       // D_K

typedef __attribute__((ext_vector_type(8))) __bf16 bf16x8;
typedef __attribute__((ext_vector_type(4))) float f32x4;

__device__ __forceinline__ float bf2f(unsigned short u) {
    union { uint32_t i; float f; } x; x.i = ((uint32_t)u) << 16; return x.f;
}
__device__ __forceinline__ unsigned short f2bf(float f) {
    union { float f; uint32_t i; } x; x.f = f;
    uint32_t r = x.i + 0x7fffu + ((x.i >> 16) & 1u);   // RNE
    return (unsigned short)(r >> 16);
}

__device__ __forceinline__ void gl2lds16(const void* g, void* l) {
    __builtin_amdgcn_global_load_lds(
        (const __attribute__((address_space(1))) void*)g,
        (__attribute__((address_space(3))) void*)l, 16, 0, 0);
}

__device__ __forceinline__ f32x4 mfma_bf16(bf16x8 a, bf16x8 b, f32x4 c) {
    return __builtin_amdgcn_mfma_f32_16x16x32_bf16(a, b, c, 0, 0, 0);
}

__device__ __forceinline__ void store_out(float* p, float v) { *p = v; }
__device__ __forceinline__ void store_out(unsigned short* p, float v) { *p = f2bf(v); }

// ---------------------------------------------------------------------------
// fp32 -> bf16 conversion, 16 segments of exactly 1M floats (2^18 float4).
// ---------------------------------------------------------------------------
struct CvtArgs {
    const float* src[16];
    unsigned short* dst[16];
};

__global__ __launch_bounds__(256) void cvt16(CvtArgs a) {
    const int t = blockIdx.x * 256 + threadIdx.x;
    const int seg = t >> 18;            // 262144 float4 per segment
    const int off = t & 0x3ffff;
    const float4 v = reinterpret_cast<const float4*>(a.src[seg])[off];
    ushort4 o;
    o.x = f2bf(v.x); o.y = f2bf(v.y); o.z = f2bf(v.z); o.w = f2bf(v.w);
    reinterpret_cast<ushort4*>(a.dst[seg])[off] = o;
}

// ---------------------------------------------------------------------------
// Batched NT GEMM, bf16 in, MFMA 16x16x32, fp32 accum:
//   C[z][M,N] = A[z][M,K] @ W[z][N,K]^T + bias[z][N]
// BMxBN tile, BK=64, 4 waves (2x2). m97 structure: global_load_lds width=16
// into linear LDS, 2-barrier K-loop.
// ---------------------------------------------------------------------------
template<typename OutT>
struct GemmArgs {
    const unsigned short* A[3];
    const unsigned short* W[3];
    const float* bias[3];
    OutT* C[3];
};

template<int BM, int BN, typename OutT>
__global__ __launch_bounds__(256) void gemm_nt_bf16(GemmArgs<OutT> g, int M, int N, int K)
{
    const unsigned short* __restrict__ A  = g.A[blockIdx.z];
    const unsigned short* __restrict__ Bw = g.W[blockIdx.z];
    const float* __restrict__ bias = g.bias[blockIdx.z];
    OutT* __restrict__ C = g.C[blockIdx.z];

    constexpr int FM = BM / 32;   // frags per wave (m)
    constexpr int FN = BN / 32;   // frags per wave (n)

    __shared__ unsigned short As[BM * 64];   // [row][k] row-major
    __shared__ unsigned short Bs[BN * 64];   // [col][k] row-major

    const int tid  = threadIdx.x;
    const int lane = tid & 63;
    const int w    = tid >> 6;          // wave 0..3
    const int wr   = w >> 1, wc = w & 1;
    const int row0 = blockIdx.y * BM;
    const int col0 = blockIdx.x * BN;

    f32x4 acc[FM][FN];
    #pragma unroll
    for (int m = 0; m < FM; ++m)
        #pragma unroll
        for (int n = 0; n < FN; ++n)
            acc[m][n] = (f32x4){0.f, 0.f, 0.f, 0.f};

    const int srow = lane >> 3;          // 0..7: row within 8-row stripe
    const int scol = (lane & 7) * 8;     // element offset within 64-elem row

    for (int kt = 0; kt < K; kt += 64) {
        // stage A,B tiles: stripes of 8 rows x 64 cols (1024B = one wave-issue)
        #pragma unroll
        for (int i = 0; i < BM / 32; ++i) {
            const int stripe = w * (BM / 32) + i;
            const int r = stripe * 8 + srow;
            gl2lds16(A + (size_t)(row0 + r) * K + kt + scol, &As[stripe * 512]);
        }
        #pragma unroll
        for (int i = 0; i < BN / 32; ++i) {
            const int stripe = w * (BN / 32) + i;
            const int r = stripe * 8 + srow;
            gl2lds16(Bw + (size_t)(col0 + r) * K + kt + scol, &Bs[stripe * 512]);
        }
        __syncthreads();   // drains vmcnt -> staged tiles visible

        #pragma unroll
        for (int kk = 0; kk < 2; ++kk) {
            const int ko = kk * 32 + (lane >> 4) * 8;
            bf16x8 af[FM], bf[FN];
            #pragma unroll
            for (int m = 0; m < FM; ++m)
                af[m] = *reinterpret_cast<const bf16x8*>(
                    &As[(wr * (BM / 2) + m * 16 + (lane & 15)) * 64 + ko]);
            #pragma unroll
            for (int n = 0; n < FN; ++n)
                bf[n] = *reinterpret_cast<const bf16x8*>(
                    &Bs[(wc * (BN / 2) + n * 16 + (lane & 15)) * 64 + ko]);
            #pragma unroll
            for (int m = 0; m < FM; ++m)
                #pragma unroll
                for (int n = 0; n < FN; ++n)
                    acc[m][n] = mfma_bf16(af[m], bf[n], acc[m][n]);
        }
        __syncthreads();   // all waves done reading before next stage
    }

    // epilogue: C/D layout col=lane&15, row=(lane>>4)*4+reg
    const int cr = (lane >> 4) * 4;
    const int cc = lane & 15;
    #pragma unroll
    for (int n = 0; n < FN; ++n) {
        const int col = col0 + wc * (BN / 2) + n * 16 + cc;
        const float bv = bias[col];
        #pragma unroll
        for (int m = 0; m < FM; ++m) {
            const int rowb = row0 + wr * (BM / 2) + m * 16 + cr;
            #pragma unroll
            for (int r = 0; r < 4; ++r)
                store_out(&C[(size_t)(rowb + r) * N + col], acc[m][n][r] + bv);
        }
    }
}

// ---------------------------------------------------------------------------
// K^T V partials per (b,h) over an s-chunk (bf16 in, fp32 accum/out):
//   Mpart[chunk,bh,d1,d2] = sum_{s in chunk, mask=1} K[b,s,h*64+d1]*V[b,s,h*64+d2]
//   cvpart[chunk,bh,e]    = sum_{s in chunk, mask=0} V[b,s,h*64+e]
// ---------------------------------------------------------------------------
__global__ __launch_bounds__(256) void ktv_partial(
    const unsigned short* __restrict__ Kb, const unsigned short* __restrict__ Vb,
    const int* __restrict__ mask, float* __restrict__ Mpart,
    float* __restrict__ cvpart, int S, int schunk)
{
    __shared__ float Ks[16][64];
    __shared__ float Vs[16][64];
    __shared__ float cvs[16][64];
    const int bh = blockIdx.x, chunk = blockIdx.y, BH = gridDim.x;
    const int b = bh >> 4, h = bh & 15;
    const int tid = threadIdx.x;
    const int tx = tid & 15, ty = tid >> 4;
    const int s0 = chunk * schunk;

    float acc[4][4] = {};
    float cv[4] = {0.f, 0.f, 0.f, 0.f};

    for (int sc = 0; sc < schunk; sc += 16) {
        const int s = s0 + sc + ty;
        const size_t rowoff = (size_t)(b * S + s) * DM + h * DK + tx * 4;
        const ushort4 kraw = *reinterpret_cast<const ushort4*>(Kb + rowoff);
        const ushort4 vraw = *reinterpret_cast<const ushort4*>(Vb + rowoff);
        float kv[4] = {bf2f(kraw.x), bf2f(kraw.y), bf2f(kraw.z), bf2f(kraw.w)};
        const float vv[4] = {bf2f(vraw.x), bf2f(vraw.y), bf2f(vraw.z), bf2f(vraw.w)};
        if (mask[b * S + s] == 0) {
            #pragma unroll
            for (int j = 0; j < 4; ++j) { cv[j] += vv[j]; kv[j] = 0.f; }
        }
        __syncthreads();
        #pragma unroll
        for (int j = 0; j < 4; ++j) { Ks[ty][tx * 4 + j] = kv[j]; Vs[ty][tx * 4 + j] = vv[j]; }
        __syncthreads();
        #pragma unroll
        for (int ss = 0; ss < 16; ++ss) {
            float kvv[4], vvv[4];
            #pragma unroll
            for (int i = 0; i < 4; ++i) kvv[i] = Ks[ss][ty * 4 + i];
            #pragma unroll
            for (int j = 0; j < 4; ++j) vvv[j] = Vs[ss][tx * 4 + j];
            #pragma unroll
            for (int i = 0; i < 4; ++i)
                #pragma unroll
                for (int j = 0; j < 4; ++j)
                    acc[i][j] += kvv[i] * vvv[j];
        }
    }

    const size_t mbase = ((size_t)chunk * BH + bh) * (DK * DK);
    #pragma unroll
    for (int i = 0; i < 4; ++i)
        #pragma unroll
        for (int j = 0; j < 4; ++j)
            Mpart[mbase + (size_t)(ty * 4 + i) * DK + tx * 4 + j] = acc[i][j];

    __syncthreads();
    #pragma unroll
    for (int j = 0; j < 4; ++j) cvs[ty][tx * 4 + j] = cv[j];
    __syncthreads();
    if (tid < DK) {
        float s = 0.f;
        #pragma unroll
        for (int r = 0; r < 16; ++r) s += cvs[r][tid];
        cvpart[((size_t)chunk * BH + bh) * DK + tid] = s;
    }
}

// ---------------------------------------------------------------------------
// Reduce partials: Mm[bh] = sum_c Mpart[c,bh] * (1/sqrt(DK)); cvec likewise.
// grid (BH, 8): each block reduces 512 of the 4096 elements.
// ---------------------------------------------------------------------------
__global__ __launch_bounds__(256) void reduce_m(
    const float* __restrict__ Mpart, const float* __restrict__ cvpart,
    float* __restrict__ Mm, float* __restrict__ cvec, int nchunk, int BH)
{
    const int bh = blockIdx.x;
    const int tid = threadIdx.x;
    const int e0 = blockIdx.y * 512;
    for (int e = e0 + tid; e < e0 + 512; e += 256) {
        float s = 0.f;
        for (int c = 0; c < nchunk; ++c)
            s += Mpart[((size_t)c * BH + bh) * (DK * DK) + e];
        Mm[(size_t)bh * DK * DK + e] = s * 0.125f;   // 1/sqrt(64)
    }
    if (blockIdx.y == 0 && tid < DK) {
        float s = 0.f;
        for (int c = 0; c < nchunk; ++c)
            s += cvpart[((size_t)c * BH + bh) * DK + tid];
        cvec[bh * DK + tid] = s;
    }
}

// ---------------------------------------------------------------------------
// attn[b,s,h*64+e] = sum_d Q[b,s,h*64+d]*Mm[bh,d,e] - 1e9*cvec[bh,e]
// Q bf16 in, attn bf16 out, fp32 math.
// ---------------------------------------------------------------------------
__global__ __launch_bounds__(256) void qm_attn(
    const unsigned short* __restrict__ Qb, const float* __restrict__ Mm,
    const float* __restrict__ cvec, unsigned short* __restrict__ attn, int S)
{
    __shared__ float Qs[64][65];
    __shared__ float Ms[64][65];
    const int bh = blockIdx.y;
    const int b = bh >> 4, h = bh & 15;
    const int s0 = blockIdx.x * 64;
    const int tid = threadIdx.x;
    const int tx = tid & 15, ty = tid >> 4;
    const int lr = tid >> 2;   // 0..63
    const int lc = tid & 3;    // 4 threads per row

    #pragma unroll
    for (int u = 0; u < 4; ++u) {
        const int f = (lc + u * 4) * 4;   // col 0..60 step 4
        const ushort4 qraw = *reinterpret_cast<const ushort4*>(
            Qb + (size_t)(b * S + s0 + lr) * DM + h * DK + f);
        Qs[lr][f + 0] = bf2f(qraw.x); Qs[lr][f + 1] = bf2f(qraw.y);
        Qs[lr][f + 2] = bf2f(qraw.z); Qs[lr][f + 3] = bf2f(qraw.w);
        const float4 mv = *reinterpret_cast<const float4*>(
            Mm + (size_t)bh * DK * DK + (size_t)lr * DK + f);
        Ms[lr][f + 0] = mv.x; Ms[lr][f + 1] = mv.y; Ms[lr][f + 2] = mv.z; Ms[lr][f + 3] = mv.w;
    }
    __syncthreads();

    float acc[4][4] = {};
    #pragma unroll 8
    for (int kk = 0; kk < 64; ++kk) {
        float qv[4], mv[4];
        #pragma unroll
        for (int i = 0; i < 4; ++i) qv[i] = Qs[ty * 4 + i][kk];
        #pragma unroll
        for (int j = 0; j < 4; ++j) mv[j] = Ms[kk][tx * 4 + j];
        #pragma unroll
        for (int i = 0; i < 4; ++i)
            #pragma unroll
            for (int j = 0; j < 4; ++j)
                acc[i][j] += qv[i] * mv[j];
    }

    float cvv[4];
    #pragma unroll
    for (int j = 0; j < 4; ++j) cvv[j] = -1.0e9f * cvec[bh * DK + tx * 4 + j];

    #pragma unroll
    for (int i = 0; i < 4; ++i) {
        const size_t orow = (size_t)(b * S + s0 + ty * 4 + i) * DM + h * DK;
        ushort4 o;
        o.x = f2bf(acc[i][0] + cvv[0]);
        o.y = f2bf(acc[i][1] + cvv[1]);
        o.z = f2bf(acc[i][2] + cvv[2]);
        o.w = f2bf(acc[i][3] + cvv[3]);
        *reinterpret_cast<ushort4*>(&attn[orow + tx * 4]) = o;
    }
}

// ---------------------------------------------------------------------------
extern "C" void kernel_launch(void* const* d_in, const int* in_sizes, int n_in,
                              void* d_out, int out_size, void* d_ws, size_t ws_size,
                              hipStream_t stream)
{
    const float* q    = (const float*)d_in[0];
    const float* k    = (const float*)d_in[1];
    const float* v    = (const float*)d_in[2];
    const int*   mask = (const int*)  d_in[3];
    const float* Wq   = (const float*)d_in[4];
    const float* bq   = (const float*)d_in[5];
    const float* Wk   = (const float*)d_in[6];
    const float* bk   = (const float*)d_in[7];
    const float* Wv   = (const float*)d_in[8];
    const float* bv   = (const float*)d_in[9];
    const float* Wo   = (const float*)d_in[10];
    const float* bo   = (const float*)d_in[11];
    float* out = (float*)d_out;

    const int BS = in_sizes[0] / DM;   // B*S = 4096
    const int B  = 2;
    const int S  = BS / B;             // 2048
    const int BH = B * NH;             // 32
    const int SCHUNK = 64;
    const int NCHUNK = S / SCHUNK;     // 32
    const size_t BSDM = (size_t)BS * DM;   // 4M
    const size_t DMDM = (size_t)DM * DM;   // 1M

    unsigned short* ws = (unsigned short*)d_ws;
    unsigned short* qb   = ws;                  // bf16 copies of inputs
    unsigned short* kb   = qb  + BSDM;
    unsigned short* vb   = kb  + BSDM;
    unsigned short* Wqb  = vb  + BSDM;
    unsigned short* Wkb  = Wqb + DMDM;
    unsigned short* Wvb  = Wkb + DMDM;
    unsigned short* Wob  = Wvb + DMDM;
    unsigned short* Qp   = Wob + DMDM;          // projection outputs (bf16)
    unsigned short* Kp   = Qp  + BSDM;
    unsigned short* Vp   = Kp  + BSDM;
    unsigned short* attnb = qb;                 // alias: qb dead after projections
    float* Mpart = (float*)kb;                  // alias: kb+vb (16MB) dead after projections
    float* cvprt = (float*)Wqb;                 // alias: Wqb dead after projections
    float* Mm    = cvprt + (size_t)NCHUNK * BH * DK;
    float* cvec  = Mm    + (size_t)BH * DK * DK;

    const dim3 blk(256);

    // fp32 -> bf16 conversions: 16 segments of exactly 1M floats, one launch
    CvtArgs cv;
    for (int i = 0; i < 4; ++i) { cv.src[0+i] = q + (size_t)i * DMDM; cv.dst[0+i] = qb + (size_t)i * DMDM; }
    for (int i = 0; i < 4; ++i) { cv.src[4+i] = k + (size_t)i * DMDM; cv.dst[4+i] = kb + (size_t)i * DMDM; }
    for (int i = 0; i < 4; ++i) { cv.src[8+i] = v + (size_t)i * DMDM; cv.dst[8+i] = vb + (size_t)i * DMDM; }
    cv.src[12] = Wq; cv.dst[12] = Wqb;
    cv.src[13] = Wk; cv.dst[13] = Wkb;
    cv.src[14] = Wv; cv.dst[14] = Wvb;
    cv.src[15] = Wo; cv.dst[15] = Wob;
    cvt16<<<dim3(16 * 1024), blk, 0, stream>>>(cv);

    // batched QKV projections (grid.z = 3 -> 768 blocks, 3/CU)
    GemmArgs<unsigned short> ga;
    ga.A[0] = qb;  ga.A[1] = kb;  ga.A[2] = vb;
    ga.W[0] = Wqb; ga.W[1] = Wkb; ga.W[2] = Wvb;
    ga.bias[0] = bq; ga.bias[1] = bk; ga.bias[2] = bv;
    ga.C[0] = Qp;  ga.C[1] = Kp;  ga.C[2] = Vp;
    gemm_nt_bf16<128, 128, unsigned short>
        <<<dim3(DM / 128, BS / 128, 3), blk, 0, stream>>>(ga, BS, DM, DM);

    // per-head K^T V (masked) partials + reduction (1024 blocks)
    ktv_partial<<<dim3(BH, NCHUNK), blk, 0, stream>>>(Kp, Vp, mask, Mpart, cvprt, S, SCHUNK);
    reduce_m<<<dim3(BH, 8), blk, 0, stream>>>(Mpart, cvprt, Mm, cvec, NCHUNK, BH);

    // attn = Q @ Mm (per head) + mask correction, bf16 out (1024 blocks)
    qm_attn<<<dim3(S / 64, BH), blk, 0, stream>>>(Qp, Mm, cvec, attnb, S);

    // output projection (fp32 out): 128x64 tiles -> 512 blocks, 2/CU
    GemmArgs<float> gf;
    gf.A[0] = attnb; gf.A[1] = nullptr; gf.A[2] = nullptr;
    gf.W[0] = Wob;   gf.W[1] = nullptr; gf.W[2] = nullptr;
    gf.bias[0] = bo; gf.bias[1] = nullptr; gf.bias[2] = nullptr;
    gf.C[0] = out;   gf.C[1] = nullptr;  gf.C[2] = nullptr;
    gemm_nt_bf16<128, 64, float>
        <<<dim3(DM / 64, BS / 128, 1), blk, 0, stream>>>(gf, BS, DM, DM);
}